// Round 8
// baseline (150.563 us; speedup 1.0000x reference)
//
#include <hip/hip_runtime.h>

// 2-layer GCN: h1 = emb[x] @ W1; agg+b1+relu; @ W2; agg+b2.
// CSR built per-launch via two-level binned counting sort (no global atomics
// per edge -- R23 measured why: atomic CSR k_deg alone = 429us, WRITE 89MB).
// R27 = R24 aggs (best measured, verbatim) + BINSHIFT 6 build: binsort was
// grid-starved (782 blocks ~= 3/CU resident -> serial per-block chain
// exposed). 1563 blocks of 64-node bins ~= 6/CU: 2x cross-block overlap,
// halved per-block phases; ldeg scan is now a SINGLE-wave shfl scan; mm1 is
// 4 threads/node. Margins: mean bin 1024, sigma 32, STRIDE/CAP 1408 (+12s).
// Amplifies R22 (BINSHIFT 8->7, the only measured win since R19: -2.2us).
// Rejected by measurement: LDS-atomic edge-parallel agg (R3); 16B-per-lane
// gathers (R10); channel-split passes (R7); cooperative fused build (R13);
// degree-sorted scheduling (R15); atomic-counter scan fusion w/ device fence
// (R16); one-node-per-wave agg (R20); launch-count reduction (R21: neutral);
// global-atomic CSR (R23: 4.5x); agg gather pipelining (R24: neutral, kept);
// persistent grid-stride aggs (R25: +5.8us); wide-MLP agg preload (R26:
// neutral).

#define BS   256
#define BSBIG 1024        // scatter block size (16 waves)
#define NBLK 256          // blocks for scatter
#define BINSHIFT 6        // 64 nodes per bin
#define BIN  64
#define MAXBINS 2048
#define BINCAP 1408       // LDS packed staging (mean bin = 1024, sigma ~32)
#define BINSTRIDE 1408    // slack region per bin in packed (+12 sigma)

union H2 { int i; _Float16 h[2]; };

// ---- fused pass A+B+C: hist (LDS) -> global base alloc -> scatter ----------
__global__ __launch_bounds__(BSBIG) void k_scatter(
    const int* __restrict__ src, const int* __restrict__ dst,
    int E, int NBINS, int* __restrict__ gbin, int* __restrict__ packed) {
    __shared__ int h[MAXBINS];
    __shared__ int cur[MAXBINS];
    int t = threadIdx.x;
    for (int i = t; i < NBINS; i += BSBIG) h[i] = 0;
    __syncthreads();
    int E4 = E >> 2;
    const int4* d4 = (const int4*)dst;
    const int4* s4 = (const int4*)src;
    // phase 1: LDS histogram of this block's slice (+ tail on block 0)
    for (int i = blockIdx.x * BSBIG + t; i < E4; i += NBLK * BSBIG) {
        int4 d = d4[i];
        atomicAdd(&h[d.x >> BINSHIFT], 1);
        atomicAdd(&h[d.y >> BINSHIFT], 1);
        atomicAdd(&h[d.z >> BINSHIFT], 1);
        atomicAdd(&h[d.w >> BINSHIFT], 1);
    }
    if (blockIdx.x == 0 && t < (E & 3))
        atomicAdd(&h[dst[(E4 << 2) + t] >> BINSHIFT], 1);
    __syncthreads();
    // phase 2: one global atomicAdd per bin -> base within slack region
    for (int i = t; i < NBINS; i += BSBIG)
        cur[i] = i * BINSTRIDE + atomicAdd(&gbin[i], h[i]);
    __syncthreads();
    // phase 3: scatter (dst slice is L1/L2-hot from phase 1)
    for (int i = blockIdx.x * BSBIG + t; i < E4; i += NBLK * BSBIG) {
        int4 s = s4[i];
        int4 d = d4[i];
        int p0 = atomicAdd(&cur[d.x >> BINSHIFT], 1);
        packed[p0] = s.x | ((d.x & (BIN - 1)) << 18);
        int p1 = atomicAdd(&cur[d.y >> BINSHIFT], 1);
        packed[p1] = s.y | ((d.y & (BIN - 1)) << 18);
        int p2 = atomicAdd(&cur[d.z >> BINSHIFT], 1);
        packed[p2] = s.z | ((d.z & (BIN - 1)) << 18);
        int p3 = atomicAdd(&cur[d.w >> BINSHIFT], 1);
        packed[p3] = s.w | ((d.w & (BIN - 1)) << 18);
    }
    if (blockIdx.x == 0 && t < (E & 3)) {
        int e = (E4 << 2) + t;
        int d = dst[e];
        int p = atomicAdd(&cur[d >> BINSHIFT], 1);
        packed[p] = src[e] | ((d & (BIN - 1)) << 18);
    }
}

// ---- pass D: per-bin counting sort (staged in LDS) + fused mm1 --------------
// e0 (global CSR base for this bin) = prefix REDUCTION over gbin[0..b-1].
// BIN=64: ldeg scan is a single-wave shfl scan; mm1 is 4 threads/node.
__global__ void k_binsort(const int* __restrict__ packed,
                          const int* __restrict__ gbin,
                          int NBINS, int N, int E,
                          const int* __restrict__ x, const float* __restrict__ emb,
                          const float* __restrict__ W1,
                          int* __restrict__ row_start, float* __restrict__ dinv,
                          int* __restrict__ col, _Float16* __restrict__ sig1) {
    __shared__ int buf[BINCAP];                  // 5.5 KB staging
    __shared__ int ldeg[BIN];
    __shared__ int cur[BIN];
    __shared__ float sW[512];                    // W1 (16x32)
    __shared__ int redw[4];                      // e0 reduction
    int b = blockIdx.x;
    int t = threadIdx.x;
    int lane = t & 63;
    int wv = t >> 6;
    int node0 = b << BINSHIFT;
    // ---- e0 = sum of gbin[0..b-1] (reduction, not scan) ----
    int ps = 0;
    for (int i = t; i < b; i += BS) ps += gbin[i];
    #pragma unroll
    for (int off = 1; off < 64; off <<= 1) ps += __shfl_xor(ps, off);
    if (lane == 0) redw[wv] = ps;
    sW[t] = W1[t];                               // overlap with reduction
    sW[t + 256] = W1[t + 256];
    if (t < BIN) ldeg[t] = 0;
    if (b == 0 && t == 0) row_start[N] = E;      // sentinel
    __syncthreads();
    int e0 = redw[0] + redw[1] + redw[2] + redw[3];
    int cnt = gbin[b];
    int p0 = b * BINSTRIDE;                      // packed region base
    bool fits = (cnt <= BINCAP);                 // uniform per block
    if (fits)
        for (int i = t; i < cnt; i += BS) buf[i] = packed[p0 + i];
    __syncthreads();
    for (int i = t; i < cnt; i += BS) {
        int v = fits ? buf[i] : packed[p0 + i];
        atomicAdd(&ldeg[((unsigned)v >> 18) & (BIN - 1)], 1);
    }
    __syncthreads();
    // ---- exclusive scan of ldeg[64]: single-wave shfl scan (wave 0) ----
    if (t < BIN) {
        int myDeg = ldeg[t];
        int inc = myDeg;
        #pragma unroll
        for (int off = 1; off < 64; off <<= 1) {
            int tmp = __shfl_up(inc, off);
            if (lane >= off) inc += tmp;
        }
        int ex = inc - myDeg;
        cur[t] = ex;
        int n = node0 + t;
        if (n < N) {
            row_start[n] = e0 + ex;
            dinv[n] = rsqrtf((float)(myDeg + 1));
        }
    }
    __syncthreads();
    for (int i = t; i < cnt; i += BS) {
        int v = fits ? buf[i] : packed[p0 + i];
        int pos = atomicAdd(&cur[((unsigned)v >> 18) & (BIN - 1)], 1);
        col[e0 + pos] = v & 0x3FFFF;
    }
    // ---- fused mm1: 4 threads per node (8 channels each) ----
    int nl = t & (BIN - 1);
    int q  = t >> 6;                             // 0..3 = output int4 index
    int n = node0 + nl;
    if (n < N) {
        float di = rsqrtf((float)(ldeg[nl] + 1));
        const float4* er = (const float4*)(emb + (size_t)x[n] * 16);
        float4 ra = er[0], rb = er[1], rc = er[2], rd = er[3];
        float ev[16] = {ra.x, ra.y, ra.z, ra.w, rb.x, rb.y, rb.z, rb.w,
                        rc.x, rc.y, rc.z, rc.w, rd.x, rd.y, rd.z, rd.w};
        H2 pk[4];
        #pragma unroll
        for (int dw = 0; dw < 4; dw++) {
            int c = q * 8 + dw * 2;
            float acc0 = 0.f, acc1 = 0.f;
            #pragma unroll
            for (int k = 0; k < 16; k++) {
                acc0 += ev[k] * sW[k * 32 + c];
                acc1 += ev[k] * sW[k * 32 + c + 1];
            }
            pk[dw].h[0] = (_Float16)(acc0 * di);
            pk[dw].h[1] = (_Float16)(acc1 * di);
        }
        int4 pv;
        pv.x = pk[0].i; pv.y = pk[1].i; pv.z = pk[2].i; pv.w = pk[3].i;
        ((int4*)sig1)[(size_t)n * 4 + q] = pv;
    }
}

// ---- fused layer-1 aggregate + b1 + relu + GEMM W2 -> sig2 (fp16) -----------
// 4 NODES per wave: lane = (node g in [0,4)) x (dword-channel cd in [0,16)).
// PIPELINED: iter k issues group k+1's 8 gathers before consuming group k's
// (col prefetched 2 groups ahead) -> consume waits at vmcnt(9), not drain.
__global__ __launch_bounds__(BS) void k_agg1mm2(
    const _Float16* __restrict__ sig1, const int* __restrict__ row_start,
    const float* __restrict__ dinv, const int* __restrict__ col,
    const float* __restrict__ b1, const float* __restrict__ W2,
    int N, _Float16* __restrict__ sig2) {
    __shared__ float hbuf[4][4][36];   // [wave][node][32 ch + pad]
    int t = threadIdx.x;
    int lane = t & 63;
    int wid = t >> 6;
    int g  = lane >> 4;                // node within wave
    int cd = lane & 15;                // dword channel (2 fp16)
    int n = blockIdx.x * 16 + wid * 4 + g;
    int nld = (n < N) ? n : N - 1;
    int rs = row_start[nld];
    int re = row_start[nld + 1];
    int dn = (n < N) ? (re - rs) : 0;
    int dnm1 = (dn > 0) ? dn - 1 : 0;
    int dm = dn;                       // wave max degree
    dm = max(dm, __shfl_xor(dm, 16));
    dm = max(dm, __shfl_xor(dm, 32));
    const int* s1i = (const int*)sig1;
    float a0 = 0.f, a1 = 0.f;
    int iters = (dm + 7) >> 3;
    int slot = cd & 7;
    int bidx = lane & 48;              // group base lane
    int colv = 0, coln = 0;
    if (iters > 0) {
        int idx = slot; if (idx > dnm1) idx = dnm1;
        colv = col[rs + idx];
    }
    if (iters > 1) {
        int idx = 8 + slot; if (idx > dnm1) idx = dnm1;
        coln = col[rs + idx];
    }
    // prologue: issue group 0's gathers
    int u0 = 0, u1 = 0, u2 = 0, u3 = 0, u4 = 0, u5 = 0, u6 = 0, u7 = 0;
    if (iters > 0) {
        int s0 = __shfl(colv, bidx + 0);
        int s1 = __shfl(colv, bidx + 1);
        int s2 = __shfl(colv, bidx + 2);
        int s3 = __shfl(colv, bidx + 3);
        int s4 = __shfl(colv, bidx + 4);
        int s5 = __shfl(colv, bidx + 5);
        int s6 = __shfl(colv, bidx + 6);
        int s7 = __shfl(colv, bidx + 7);
        u0 = s1i[s0 * 16 + cd];        // 8 rows (64B lines) in flight
        u1 = s1i[s1 * 16 + cd];
        u2 = s1i[s2 * 16 + cd];
        u3 = s1i[s3 * 16 + cd];
        u4 = s1i[s4 * 16 + cd];
        u5 = s1i[s5 * 16 + cd];
        u6 = s1i[s6 * 16 + cd];
        u7 = s1i[s7 * 16 + cd];
    }
    for (int it = 0; it < iters; it++) {
        int colnn = 0;
        if (it + 2 < iters) {
            int idx = ((it + 2) << 3) + slot; if (idx > dnm1) idx = dnm1;
            colnn = col[rs + idx];     // col prefetch 2 groups ahead
        }
        // issue NEXT group's gathers before consuming current
        int v0 = 0, v1 = 0, v2 = 0, v3 = 0, v4 = 0, v5 = 0, v6 = 0, v7 = 0;
        if (it + 1 < iters) {
            int s0 = __shfl(coln, bidx + 0);
            int s1 = __shfl(coln, bidx + 1);
            int s2 = __shfl(coln, bidx + 2);
            int s3 = __shfl(coln, bidx + 3);
            int s4 = __shfl(coln, bidx + 4);
            int s5 = __shfl(coln, bidx + 5);
            int s6 = __shfl(coln, bidx + 6);
            int s7 = __shfl(coln, bidx + 7);
            v0 = s1i[s0 * 16 + cd];
            v1 = s1i[s1 * 16 + cd];
            v2 = s1i[s2 * 16 + cd];
            v3 = s1i[s3 * 16 + cd];
            v4 = s1i[s4 * 16 + cd];
            v5 = s1i[s5 * 16 + cd];
            v6 = s1i[s6 * 16 + cd];
            v7 = s1i[s7 * 16 + cd];
        }
        // consume current group (waits only for u0..u7: vmcnt(9))
        int e = it << 3;
        int w0 = (e + 0 < dn) ? u0 : 0;    // 0x0 == +0.0 fp16 pair
        int w1 = (e + 1 < dn) ? u1 : 0;
        int w2 = (e + 2 < dn) ? u2 : 0;
        int w3 = (e + 3 < dn) ? u3 : 0;
        int w4 = (e + 4 < dn) ? u4 : 0;
        int w5 = (e + 5 < dn) ? u5 : 0;
        int w6 = (e + 6 < dn) ? u6 : 0;
        int w7 = (e + 7 < dn) ? u7 : 0;
        H2 p0, p1, p2, p3;
        p0.i = w0; p1.i = w1; p2.i = w2; p3.i = w3;
        a0 += ((float)p0.h[0] + (float)p1.h[0]) + ((float)p2.h[0] + (float)p3.h[0]);
        a1 += ((float)p0.h[1] + (float)p1.h[1]) + ((float)p2.h[1] + (float)p3.h[1]);
        p0.i = w4; p1.i = w5; p2.i = w6; p3.i = w7;
        a0 += ((float)p0.h[0] + (float)p1.h[0]) + ((float)p2.h[0] + (float)p3.h[0]);
        a1 += ((float)p0.h[1] + (float)p1.h[1]) + ((float)p2.h[1] + (float)p3.h[1]);
        u0 = v0; u1 = v1; u2 = v2; u3 = v3;
        u4 = v4; u5 = v5; u6 = v6; u7 = v7;
        colv = coln; coln = colnn;
    }
    {   // self-loop (pre-scaled row)
        H2 p; p.i = s1i[nld * 16 + cd];
        a0 += (float)p.h[0];
        a1 += (float)p.h[1];
    }
    float di = dinv[nld];
    float2 b = ((const float2*)b1)[cd];
    float h0 = fmaxf(a0 * di + b.x, 0.f);
    float h1 = fmaxf(a1 * di + b.y, 0.f);
    float* hb = hbuf[wid][g];
    *(float2*)&hb[2 * cd] = make_float2(h0, h1);
    // w2c loaded HERE (epilogue-only use; keeps main-loop VGPR pressure low,
    // and the global loads cover the ds_write->ds_read latency)
    float w2c[32];
    #pragma unroll
    for (int k = 0; k < 32; k++) w2c[k] = W2[k * 16 + cd];
    // same-wave LDS produce->consume: in-order ds ops + lgkmcnt, no barrier
    float a = 0.f;
    #pragma unroll
    for (int k = 0; k < 32; k += 4) {
        float4 hv = *(const float4*)&hb[k];
        a = fmaf(hv.x, w2c[k],     a);
        a = fmaf(hv.y, w2c[k + 1], a);
        a = fmaf(hv.z, w2c[k + 2], a);
        a = fmaf(hv.w, w2c[k + 3], a);
    }
    if (n < N) sig2[(size_t)n * 16 + cd] = (_Float16)(a * di);   // pre-scale
}

// ---- layer-2 aggregate + b2 -> out ------------------------------------------
// 4 NODES per wave: lane = (node g) x (edge-half e2) x (dword cd in [0,8)).
// PIPELINED like agg1: next group's 8 gathers issued before consuming current.
__global__ __launch_bounds__(BS) void k_agg2(
    const _Float16* __restrict__ sig2, const int* __restrict__ row_start,
    const float* __restrict__ dinv, const int* __restrict__ col,
    const float* __restrict__ b2, int N, float* __restrict__ out) {
    int t = threadIdx.x;
    int lane = t & 63;
    int g  = lane >> 4;                // node within wave
    int e2 = (lane >> 3) & 1;          // edge half
    int cd = lane & 7;                 // dword channel (2 fp16)
    int n = blockIdx.x * 16 + (t >> 6) * 4 + g;
    int nld = (n < N) ? n : N - 1;
    int rs = row_start[nld];
    int re = row_start[nld + 1];
    int dn = (n < N) ? (re - rs) : 0;
    int dnm1 = (dn > 0) ? dn - 1 : 0;
    int dm = dn;
    dm = max(dm, __shfl_xor(dm, 16));
    dm = max(dm, __shfl_xor(dm, 32));
    const int* s2i = (const int*)sig2;
    float a0 = 0.f, a1 = 0.f;
    int iters = (dm + 15) >> 4;
    int slot = lane & 15;              // this lane's col slot (0..15)
    int bidx = lane & 48;
    int colv = 0, coln = 0;
    if (iters > 0) {
        int idx = slot; if (idx > dnm1) idx = dnm1;
        colv = col[rs + idx];
    }
    if (iters > 1) {
        int idx = 16 + slot; if (idx > dnm1) idx = dnm1;
        coln = col[rs + idx];
    }
    // prologue: issue group 0's gathers (8 per lane; each inst = 8 rows)
    int u0 = 0, u1 = 0, u2 = 0, u3 = 0, u4 = 0, u5 = 0, u6 = 0, u7 = 0;
    if (iters > 0) {
        int s0 = __shfl(colv, bidx + 0 + e2);
        int s1 = __shfl(colv, bidx + 2 + e2);
        int s2 = __shfl(colv, bidx + 4 + e2);
        int s3 = __shfl(colv, bidx + 6 + e2);
        int s4 = __shfl(colv, bidx + 8 + e2);
        int s5 = __shfl(colv, bidx + 10 + e2);
        int s6 = __shfl(colv, bidx + 12 + e2);
        int s7 = __shfl(colv, bidx + 14 + e2);
        u0 = s2i[s0 * 8 + cd];
        u1 = s2i[s1 * 8 + cd];
        u2 = s2i[s2 * 8 + cd];
        u3 = s2i[s3 * 8 + cd];
        u4 = s2i[s4 * 8 + cd];
        u5 = s2i[s5 * 8 + cd];
        u6 = s2i[s6 * 8 + cd];
        u7 = s2i[s7 * 8 + cd];
    }
    for (int it = 0; it < iters; it++) {
        int colnn = 0;
        if (it + 2 < iters) {
            int idx = ((it + 2) << 4) + slot; if (idx > dnm1) idx = dnm1;
            colnn = col[rs + idx];     // col prefetch 2 groups ahead
        }
        int v0 = 0, v1 = 0, v2 = 0, v3 = 0, v4 = 0, v5 = 0, v6 = 0, v7 = 0;
        if (it + 1 < iters) {
            int s0 = __shfl(coln, bidx + 0 + e2);
            int s1 = __shfl(coln, bidx + 2 + e2);
            int s2 = __shfl(coln, bidx + 4 + e2);
            int s3 = __shfl(coln, bidx + 6 + e2);
            int s4 = __shfl(coln, bidx + 8 + e2);
            int s5 = __shfl(coln, bidx + 10 + e2);
            int s6 = __shfl(coln, bidx + 12 + e2);
            int s7 = __shfl(coln, bidx + 14 + e2);
            v0 = s2i[s0 * 8 + cd];
            v1 = s2i[s1 * 8 + cd];
            v2 = s2i[s2 * 8 + cd];
            v3 = s2i[s3 * 8 + cd];
            v4 = s2i[s4 * 8 + cd];
            v5 = s2i[s5 * 8 + cd];
            v6 = s2i[s6 * 8 + cd];
            v7 = s2i[s7 * 8 + cd];
        }
        int e = it << 4;
        int w0 = (e + 0  + e2 < dn) ? u0 : 0;
        int w1 = (e + 2  + e2 < dn) ? u1 : 0;
        int w2 = (e + 4  + e2 < dn) ? u2 : 0;
        int w3 = (e + 6  + e2 < dn) ? u3 : 0;
        int w4 = (e + 8  + e2 < dn) ? u4 : 0;
        int w5 = (e + 10 + e2 < dn) ? u5 : 0;
        int w6 = (e + 12 + e2 < dn) ? u6 : 0;
        int w7 = (e + 14 + e2 < dn) ? u7 : 0;
        H2 p0, p1, p2, p3;
        p0.i = w0; p1.i = w1; p2.i = w2; p3.i = w3;
        a0 += ((float)p0.h[0] + (float)p1.h[0]) + ((float)p2.h[0] + (float)p3.h[0]);
        a1 += ((float)p0.h[1] + (float)p1.h[1]) + ((float)p2.h[1] + (float)p3.h[1]);
        p0.i = w4; p1.i = w5; p2.i = w6; p3.i = w7;
        a0 += ((float)p0.h[0] + (float)p1.h[0]) + ((float)p2.h[0] + (float)p3.h[0]);
        a1 += ((float)p0.h[1] + (float)p1.h[1]) + ((float)p2.h[1] + (float)p3.h[1]);
        u0 = v0; u1 = v1; u2 = v2; u3 = v3;
        u4 = v4; u5 = v5; u6 = v6; u7 = v7;
        colv = coln; coln = colnn;
    }
    a0 += __shfl_xor(a0, 8);           // combine edge halves
    a1 += __shfl_xor(a1, 8);
    {   // self-loop
        H2 p; p.i = s2i[nld * 8 + cd];
        a0 += (float)p.h[0];
        a1 += (float)p.h[1];
    }
    if (n < N && e2 == 0) {
        float di = dinv[nld];
        float2 b = ((const float2*)b2)[cd];
        float2 o;
        o.x = a0 * di + b.x;
        o.y = a1 * di + b.y;
        ((float2*)out)[(size_t)n * 8 + cd] = o;
    }
}

extern "C" void kernel_launch(void* const* d_in, const int* in_sizes, int n_in,
                              void* d_out, int out_size, void* d_ws, size_t ws_size,
                              hipStream_t stream) {
    const int*   x   = (const int*)d_in[0];
    const int*   ei  = (const int*)d_in[1];
    const float* emb = (const float*)d_in[2];
    const float* W1  = (const float*)d_in[3];
    const float* b1  = (const float*)d_in[4];
    const float* W2  = (const float*)d_in[5];
    const float* b2  = (const float*)d_in[6];
    float* out = (float*)d_out;

    const int N = in_sizes[0];
    const int E = in_sizes[1] / 2;
    const int* srcp = ei;
    const int* dstp = ei + E;
    const int NBINS = (N + BIN - 1) >> BINSHIFT;   // 1563 for N=100000

    auto al = [](size_t b) { return (b + 255) & ~size_t(255); };
    char* w = (char*)d_ws;
    auto carve = [&](size_t bytes) {
        void* p = (void*)w;
        w += al(bytes);
        return p;
    };
    // no unions: binsort writes sig1 while other blocks still read packed.
    int*   row_start = (int*)carve((size_t)(N + 1) * 4);
    float* dinv      = (float*)carve((size_t)N * 4);
    int*   col       = (int*)carve((size_t)(E + 256) * 4);  // +pad for clamped reads
    int*   gbin      = (int*)carve((size_t)NBINS * 4);
    int*   packed    = (int*)carve((size_t)NBINS * BINSTRIDE * 4);
    _Float16* sig1   = (_Float16*)carve((size_t)N * 32 * 2);
    _Float16* sig2   = (_Float16*)carve((size_t)N * 16 * 2);
    (void)ws_size; (void)n_in; (void)out_size;

    hipMemsetAsync(gbin, 0, (size_t)NBINS * 4, stream);
    k_scatter<<<NBLK, BSBIG, 0, stream>>>(srcp, dstp, E, NBINS, gbin, packed);
    k_binsort<<<NBINS, BS, 0, stream>>>(packed, gbin, NBINS, N, E,
                                        x, emb, W1, row_start, dinv, col, sig1);

    int gA = (N + 15) / 16;            // 4 waves x 4 nodes per block
    k_agg1mm2<<<gA, BS, 0, stream>>>(sig1, row_start, dinv, col, b1, W2, N, sig2);
    k_agg2<<<gA, BS, 0, stream>>>(sig2, row_start, dinv, col, b2, N, out);
}

// Round 9
// 149.591 us; speedup vs baseline: 1.0065x; 1.0065x over previous
//
#include <hip/hip_runtime.h>

// 2-layer GCN: h1 = emb[x] @ W1; agg+b1+relu; @ W2; agg+b2.
// CSR built per-launch via two-level binned counting sort (no global atomics
// per edge -- R23 measured why: atomic CSR k_deg alone = 429us, WRITE 89MB).
// R28 = R24 (best measured, 147.6us) + PAIRED 64-bit gbin reservation
// atomics: k_scatter phase 2 previously did 200K cross-XCD atomicAdds on 782
// shared lines (R23 taught same-line cross-XCD atomics serialize ~100ns).
// Packing bin pairs into one ull atomicAdd halves ops (100K) and contended
// lines (391). Halves can't carry (max count 4350 << 2^32). binsort reads
// pairs. Zero numeric change. R27 (BINSHIFT 6) regressed +3us: e0 prefix
// cost doubles as bins shrink -- reverted to BINSHIFT 7.
// Rejected by measurement: LDS-atomic edge-parallel agg (R3); 16B-per-lane
// gathers (R10); channel-split passes (R7); cooperative fused build (R13);
// degree-sorted scheduling (R15); atomic-counter scan fusion w/ device fence
// (R16); one-node-per-wave agg (R20); launch-count reduction (R21: neutral);
// global-atomic CSR (R23: 4.5x); persistent grid-stride aggs (R25: +5.8us);
// wide-MLP agg preload (R26: neutral); BINSHIFT 6 (R27: +3us).

#define BS   256
#define BSBIG 1024        // scatter block size (16 waves)
#define NBLK 256          // blocks for scatter
#define BINSHIFT 7        // 128 nodes per bin
#define BIN  128
#define MAXBINS 1024
#define BINCAP 2560       // LDS packed staging (mean bin = 2046, sigma ~45)
#define BINSTRIDE 2560    // slack region per bin in packed (+11 sigma)

union H2 { int i; _Float16 h[2]; };

// ---- fused pass A+B+C: hist (LDS) -> global base alloc -> scatter ----------
// gbin64[j] packs counts of bins (2j, 2j+1) in (lo, hi) halves; ONE ull
// atomicAdd reserves both -> half the cross-XCD contended lines and ops.
__global__ __launch_bounds__(BSBIG) void k_scatter(
    const int* __restrict__ src, const int* __restrict__ dst,
    int E, int NBINS, unsigned long long* __restrict__ gbin64,
    int* __restrict__ packed) {
    __shared__ int h[MAXBINS];
    __shared__ int cur[MAXBINS];
    int t = threadIdx.x;
    int NB2 = (NBINS + 1) >> 1;
    for (int i = t; i < 2 * NB2; i += BSBIG) h[i] = 0;
    __syncthreads();
    int E4 = E >> 2;
    const int4* d4 = (const int4*)dst;
    const int4* s4 = (const int4*)src;
    // phase 1: LDS histogram of this block's slice (+ tail on block 0)
    for (int i = blockIdx.x * BSBIG + t; i < E4; i += NBLK * BSBIG) {
        int4 d = d4[i];
        atomicAdd(&h[d.x >> BINSHIFT], 1);
        atomicAdd(&h[d.y >> BINSHIFT], 1);
        atomicAdd(&h[d.z >> BINSHIFT], 1);
        atomicAdd(&h[d.w >> BINSHIFT], 1);
    }
    if (blockIdx.x == 0 && t < (E & 3))
        atomicAdd(&h[dst[(E4 << 2) + t] >> BINSHIFT], 1);
    __syncthreads();
    // phase 2: one ull atomicAdd per bin PAIR -> bases within slack regions
    for (int j = t; j < NB2; j += BSBIG) {
        unsigned long long comb = (unsigned long long)(unsigned)h[2 * j]
                                | ((unsigned long long)(unsigned)h[2 * j + 1] << 32);
        unsigned long long old = atomicAdd(&gbin64[j], comb);
        cur[2 * j]     = (2 * j) * BINSTRIDE + (int)(old & 0xffffffffULL);
        cur[2 * j + 1] = (2 * j + 1) * BINSTRIDE + (int)(old >> 32);
    }
    __syncthreads();
    // phase 3: scatter (dst slice is L1/L2-hot from phase 1)
    for (int i = blockIdx.x * BSBIG + t; i < E4; i += NBLK * BSBIG) {
        int4 s = s4[i];
        int4 d = d4[i];
        int p0 = atomicAdd(&cur[d.x >> BINSHIFT], 1);
        packed[p0] = s.x | ((d.x & (BIN - 1)) << 18);
        int p1 = atomicAdd(&cur[d.y >> BINSHIFT], 1);
        packed[p1] = s.y | ((d.y & (BIN - 1)) << 18);
        int p2 = atomicAdd(&cur[d.z >> BINSHIFT], 1);
        packed[p2] = s.z | ((d.z & (BIN - 1)) << 18);
        int p3 = atomicAdd(&cur[d.w >> BINSHIFT], 1);
        packed[p3] = s.w | ((d.w & (BIN - 1)) << 18);
    }
    if (blockIdx.x == 0 && t < (E & 3)) {
        int e = (E4 << 2) + t;
        int d = dst[e];
        int p = atomicAdd(&cur[d >> BINSHIFT], 1);
        packed[p] = src[e] | ((d & (BIN - 1)) << 18);
    }
}

// ---- pass D: per-bin counting sort (staged in LDS) + fused mm1 --------------
// e0 (global CSR base for this bin) = prefix REDUCTION over gbin[0..b-1],
// reading 64-bit pairs (both halves for full pairs + lo half if b odd).
__global__ void k_binsort(const int* __restrict__ packed,
                          const unsigned long long* __restrict__ gbin64,
                          int NBINS, int N, int E,
                          const int* __restrict__ x, const float* __restrict__ emb,
                          const float* __restrict__ W1,
                          int* __restrict__ row_start, float* __restrict__ dinv,
                          int* __restrict__ col, _Float16* __restrict__ sig1) {
    __shared__ int buf[BINCAP];                  // 10 KB staging
    __shared__ int ldeg[BIN];
    __shared__ int cur[BIN];
    __shared__ float sW[512];                    // W1 (16x32)
    __shared__ int redw[4];                      // e0 reduction
    __shared__ int wtot[2];                      // ldeg scan wave totals
    int b = blockIdx.x;
    int t = threadIdx.x;
    int lane = t & 63;
    int wv = t >> 6;
    int node0 = b << BINSHIFT;
    // ---- e0 = sum of gbin[0..b-1] via pair reduction ----
    int ps = 0;
    int nfull = b >> 1;                          // full pairs below b
    for (int j = t; j < nfull; j += BS) {
        unsigned long long p = gbin64[j];
        ps += (int)(p & 0xffffffffULL) + (int)(p >> 32);
    }
    if (t == 0 && (b & 1))
        ps += (int)(gbin64[nfull] & 0xffffffffULL);
    #pragma unroll
    for (int off = 1; off < 64; off <<= 1) ps += __shfl_xor(ps, off);
    if (lane == 0) redw[wv] = ps;
    sW[t] = W1[t];                               // overlap with reduction
    sW[t + 256] = W1[t + 256];
    if (t < BIN) ldeg[t] = 0;
    if (b == 0 && t == 0) row_start[N] = E;      // sentinel
    __syncthreads();
    int e0 = redw[0] + redw[1] + redw[2] + redw[3];
    unsigned long long pb = gbin64[b >> 1];
    int cnt = (b & 1) ? (int)(pb >> 32) : (int)(pb & 0xffffffffULL);
    int p0 = b * BINSTRIDE;                      // packed region base
    bool fits = (cnt <= BINCAP);                 // uniform per block
    if (fits)
        for (int i = t; i < cnt; i += BS) buf[i] = packed[p0 + i];
    __syncthreads();
    for (int i = t; i < cnt; i += BS) {
        int v = fits ? buf[i] : packed[p0 + i];
        atomicAdd(&ldeg[((unsigned)v >> 18) & (BIN - 1)], 1);
    }
    __syncthreads();
    // ---- exclusive scan of ldeg[128] via 2-wave shfl scan (1 barrier) ----
    int myDeg = 0, inc = 0;
    if (t < BIN) {
        myDeg = ldeg[t];
        inc = myDeg;
        #pragma unroll
        for (int off = 1; off < 64; off <<= 1) {
            int tmp = __shfl_up(inc, off);
            if (lane >= off) inc += tmp;
        }
        if (lane == 63) wtot[wv] = inc;
    }
    __syncthreads();
    if (t < BIN) {
        int pre = (wv == 1) ? wtot[0] : 0;
        int ex = (inc - myDeg) + pre;
        cur[t] = ex;
        int n = node0 + t;
        if (n < N) {
            row_start[n] = e0 + ex;
            dinv[n] = rsqrtf((float)(myDeg + 1));
        }
    }
    __syncthreads();
    for (int i = t; i < cnt; i += BS) {
        int v = fits ? buf[i] : packed[p0 + i];
        int pos = atomicAdd(&cur[((unsigned)v >> 18) & (BIN - 1)], 1);
        col[e0 + pos] = v & 0x3FFFF;
    }
    // ---- fused mm1: 2 threads per node (16 channels each) ----
    int nl = t & (BIN - 1);
    int half = t >> 7;                           // 0 or 1
    int n = node0 + nl;
    if (n < N) {
        float di = rsqrtf((float)(ldeg[nl] + 1));
        const float4* er = (const float4*)(emb + (size_t)x[n] * 16);
        float4 ra = er[0], rb = er[1], rc = er[2], rd = er[3];
        float ev[16] = {ra.x, ra.y, ra.z, ra.w, rb.x, rb.y, rb.z, rb.w,
                        rc.x, rc.y, rc.z, rc.w, rd.x, rd.y, rd.z, rd.w};
        int4* s1o = (int4*)sig1;
        #pragma unroll
        for (int cq2 = 0; cq2 < 2; cq2++) {
            int cq = half * 2 + cq2;
            H2 pk[4];
            #pragma unroll
            for (int dw = 0; dw < 4; dw++) {
                int c = cq * 8 + dw * 2;
                float acc0 = 0.f, acc1 = 0.f;
                #pragma unroll
                for (int k = 0; k < 16; k++) {
                    acc0 += ev[k] * sW[k * 32 + c];
                    acc1 += ev[k] * sW[k * 32 + c + 1];
                }
                pk[dw].h[0] = (_Float16)(acc0 * di);
                pk[dw].h[1] = (_Float16)(acc1 * di);
            }
            int4 pv;
            pv.x = pk[0].i; pv.y = pk[1].i; pv.z = pk[2].i; pv.w = pk[3].i;
            s1o[(size_t)n * 4 + cq] = pv;
        }
    }
}

// ---- fused layer-1 aggregate + b1 + relu + GEMM W2 -> sig2 (fp16) -----------
// 4 NODES per wave: lane = (node g in [0,4)) x (dword-channel cd in [0,16)).
// PIPELINED: iter k issues group k+1's 8 gathers before consuming group k's
// (col prefetched 2 groups ahead) -> consume waits at vmcnt(9), not drain.
__global__ __launch_bounds__(BS) void k_agg1mm2(
    const _Float16* __restrict__ sig1, const int* __restrict__ row_start,
    const float* __restrict__ dinv, const int* __restrict__ col,
    const float* __restrict__ b1, const float* __restrict__ W2,
    int N, _Float16* __restrict__ sig2) {
    __shared__ float hbuf[4][4][36];   // [wave][node][32 ch + pad]
    int t = threadIdx.x;
    int lane = t & 63;
    int wid = t >> 6;
    int g  = lane >> 4;                // node within wave
    int cd = lane & 15;                // dword channel (2 fp16)
    int n = blockIdx.x * 16 + wid * 4 + g;
    int nld = (n < N) ? n : N - 1;
    int rs = row_start[nld];
    int re = row_start[nld + 1];
    int dn = (n < N) ? (re - rs) : 0;
    int dnm1 = (dn > 0) ? dn - 1 : 0;
    int dm = dn;                       // wave max degree
    dm = max(dm, __shfl_xor(dm, 16));
    dm = max(dm, __shfl_xor(dm, 32));
    const int* s1i = (const int*)sig1;
    float a0 = 0.f, a1 = 0.f;
    int iters = (dm + 7) >> 3;
    int slot = cd & 7;
    int bidx = lane & 48;              // group base lane
    int colv = 0, coln = 0;
    if (iters > 0) {
        int idx = slot; if (idx > dnm1) idx = dnm1;
        colv = col[rs + idx];
    }
    if (iters > 1) {
        int idx = 8 + slot; if (idx > dnm1) idx = dnm1;
        coln = col[rs + idx];
    }
    // prologue: issue group 0's gathers
    int u0 = 0, u1 = 0, u2 = 0, u3 = 0, u4 = 0, u5 = 0, u6 = 0, u7 = 0;
    if (iters > 0) {
        int s0 = __shfl(colv, bidx + 0);
        int s1 = __shfl(colv, bidx + 1);
        int s2 = __shfl(colv, bidx + 2);
        int s3 = __shfl(colv, bidx + 3);
        int s4 = __shfl(colv, bidx + 4);
        int s5 = __shfl(colv, bidx + 5);
        int s6 = __shfl(colv, bidx + 6);
        int s7 = __shfl(colv, bidx + 7);
        u0 = s1i[s0 * 16 + cd];        // 8 rows (64B lines) in flight
        u1 = s1i[s1 * 16 + cd];
        u2 = s1i[s2 * 16 + cd];
        u3 = s1i[s3 * 16 + cd];
        u4 = s1i[s4 * 16 + cd];
        u5 = s1i[s5 * 16 + cd];
        u6 = s1i[s6 * 16 + cd];
        u7 = s1i[s7 * 16 + cd];
    }
    for (int it = 0; it < iters; it++) {
        int colnn = 0;
        if (it + 2 < iters) {
            int idx = ((it + 2) << 3) + slot; if (idx > dnm1) idx = dnm1;
            colnn = col[rs + idx];     // col prefetch 2 groups ahead
        }
        // issue NEXT group's gathers before consuming current
        int v0 = 0, v1 = 0, v2 = 0, v3 = 0, v4 = 0, v5 = 0, v6 = 0, v7 = 0;
        if (it + 1 < iters) {
            int s0 = __shfl(coln, bidx + 0);
            int s1 = __shfl(coln, bidx + 1);
            int s2 = __shfl(coln, bidx + 2);
            int s3 = __shfl(coln, bidx + 3);
            int s4 = __shfl(coln, bidx + 4);
            int s5 = __shfl(coln, bidx + 5);
            int s6 = __shfl(coln, bidx + 6);
            int s7 = __shfl(coln, bidx + 7);
            v0 = s1i[s0 * 16 + cd];
            v1 = s1i[s1 * 16 + cd];
            v2 = s1i[s2 * 16 + cd];
            v3 = s1i[s3 * 16 + cd];
            v4 = s1i[s4 * 16 + cd];
            v5 = s1i[s5 * 16 + cd];
            v6 = s1i[s6 * 16 + cd];
            v7 = s1i[s7 * 16 + cd];
        }
        // consume current group (waits only for u0..u7: vmcnt(9))
        int e = it << 3;
        int w0 = (e + 0 < dn) ? u0 : 0;    // 0x0 == +0.0 fp16 pair
        int w1 = (e + 1 < dn) ? u1 : 0;
        int w2 = (e + 2 < dn) ? u2 : 0;
        int w3 = (e + 3 < dn) ? u3 : 0;
        int w4 = (e + 4 < dn) ? u4 : 0;
        int w5 = (e + 5 < dn) ? u5 : 0;
        int w6 = (e + 6 < dn) ? u6 : 0;
        int w7 = (e + 7 < dn) ? u7 : 0;
        H2 p0, p1, p2, p3;
        p0.i = w0; p1.i = w1; p2.i = w2; p3.i = w3;
        a0 += ((float)p0.h[0] + (float)p1.h[0]) + ((float)p2.h[0] + (float)p3.h[0]);
        a1 += ((float)p0.h[1] + (float)p1.h[1]) + ((float)p2.h[1] + (float)p3.h[1]);
        p0.i = w4; p1.i = w5; p2.i = w6; p3.i = w7;
        a0 += ((float)p0.h[0] + (float)p1.h[0]) + ((float)p2.h[0] + (float)p3.h[0]);
        a1 += ((float)p0.h[1] + (float)p1.h[1]) + ((float)p2.h[1] + (float)p3.h[1]);
        u0 = v0; u1 = v1; u2 = v2; u3 = v3;
        u4 = v4; u5 = v5; u6 = v6; u7 = v7;
        colv = coln; coln = colnn;
    }
    {   // self-loop (pre-scaled row)
        H2 p; p.i = s1i[nld * 16 + cd];
        a0 += (float)p.h[0];
        a1 += (float)p.h[1];
    }
    float di = dinv[nld];
    float2 b = ((const float2*)b1)[cd];
    float h0 = fmaxf(a0 * di + b.x, 0.f);
    float h1 = fmaxf(a1 * di + b.y, 0.f);
    float* hb = hbuf[wid][g];
    *(float2*)&hb[2 * cd] = make_float2(h0, h1);
    // w2c loaded HERE (epilogue-only use; keeps main-loop VGPR pressure low,
    // and the global loads cover the ds_write->ds_read latency)
    float w2c[32];
    #pragma unroll
    for (int k = 0; k < 32; k++) w2c[k] = W2[k * 16 + cd];
    // same-wave LDS produce->consume: in-order ds ops + lgkmcnt, no barrier
    float a = 0.f;
    #pragma unroll
    for (int k = 0; k < 32; k += 4) {
        float4 hv = *(const float4*)&hb[k];
        a = fmaf(hv.x, w2c[k],     a);
        a = fmaf(hv.y, w2c[k + 1], a);
        a = fmaf(hv.z, w2c[k + 2], a);
        a = fmaf(hv.w, w2c[k + 3], a);
    }
    if (n < N) sig2[(size_t)n * 16 + cd] = (_Float16)(a * di);   // pre-scale
}

// ---- layer-2 aggregate + b2 -> out ------------------------------------------
// 4 NODES per wave: lane = (node g) x (edge-half e2) x (dword cd in [0,8)).
// PIPELINED like agg1: next group's 8 gathers issued before consuming current.
__global__ __launch_bounds__(BS) void k_agg2(
    const _Float16* __restrict__ sig2, const int* __restrict__ row_start,
    const float* __restrict__ dinv, const int* __restrict__ col,
    const float* __restrict__ b2, int N, float* __restrict__ out) {
    int t = threadIdx.x;
    int lane = t & 63;
    int g  = lane >> 4;                // node within wave
    int e2 = (lane >> 3) & 1;          // edge half
    int cd = lane & 7;                 // dword channel (2 fp16)
    int n = blockIdx.x * 16 + (t >> 6) * 4 + g;
    int nld = (n < N) ? n : N - 1;
    int rs = row_start[nld];
    int re = row_start[nld + 1];
    int dn = (n < N) ? (re - rs) : 0;
    int dnm1 = (dn > 0) ? dn - 1 : 0;
    int dm = dn;
    dm = max(dm, __shfl_xor(dm, 16));
    dm = max(dm, __shfl_xor(dm, 32));
    const int* s2i = (const int*)sig2;
    float a0 = 0.f, a1 = 0.f;
    int iters = (dm + 15) >> 4;
    int slot = lane & 15;              // this lane's col slot (0..15)
    int bidx = lane & 48;
    int colv = 0, coln = 0;
    if (iters > 0) {
        int idx = slot; if (idx > dnm1) idx = dnm1;
        colv = col[rs + idx];
    }
    if (iters > 1) {
        int idx = 16 + slot; if (idx > dnm1) idx = dnm1;
        coln = col[rs + idx];
    }
    // prologue: issue group 0's gathers (8 per lane; each inst = 8 rows)
    int u0 = 0, u1 = 0, u2 = 0, u3 = 0, u4 = 0, u5 = 0, u6 = 0, u7 = 0;
    if (iters > 0) {
        int s0 = __shfl(colv, bidx + 0 + e2);
        int s1 = __shfl(colv, bidx + 2 + e2);
        int s2 = __shfl(colv, bidx + 4 + e2);
        int s3 = __shfl(colv, bidx + 6 + e2);
        int s4 = __shfl(colv, bidx + 8 + e2);
        int s5 = __shfl(colv, bidx + 10 + e2);
        int s6 = __shfl(colv, bidx + 12 + e2);
        int s7 = __shfl(colv, bidx + 14 + e2);
        u0 = s2i[s0 * 8 + cd];
        u1 = s2i[s1 * 8 + cd];
        u2 = s2i[s2 * 8 + cd];
        u3 = s2i[s3 * 8 + cd];
        u4 = s2i[s4 * 8 + cd];
        u5 = s2i[s5 * 8 + cd];
        u6 = s2i[s6 * 8 + cd];
        u7 = s2i[s7 * 8 + cd];
    }
    for (int it = 0; it < iters; it++) {
        int colnn = 0;
        if (it + 2 < iters) {
            int idx = ((it + 2) << 4) + slot; if (idx > dnm1) idx = dnm1;
            colnn = col[rs + idx];     // col prefetch 2 groups ahead
        }
        int v0 = 0, v1 = 0, v2 = 0, v3 = 0, v4 = 0, v5 = 0, v6 = 0, v7 = 0;
        if (it + 1 < iters) {
            int s0 = __shfl(coln, bidx + 0 + e2);
            int s1 = __shfl(coln, bidx + 2 + e2);
            int s2 = __shfl(coln, bidx + 4 + e2);
            int s3 = __shfl(coln, bidx + 6 + e2);
            int s4 = __shfl(coln, bidx + 8 + e2);
            int s5 = __shfl(coln, bidx + 10 + e2);
            int s6 = __shfl(coln, bidx + 12 + e2);
            int s7 = __shfl(coln, bidx + 14 + e2);
            v0 = s2i[s0 * 8 + cd];
            v1 = s2i[s1 * 8 + cd];
            v2 = s2i[s2 * 8 + cd];
            v3 = s2i[s3 * 8 + cd];
            v4 = s2i[s4 * 8 + cd];
            v5 = s2i[s5 * 8 + cd];
            v6 = s2i[s6 * 8 + cd];
            v7 = s2i[s7 * 8 + cd];
        }
        int e = it << 4;
        int w0 = (e + 0  + e2 < dn) ? u0 : 0;
        int w1 = (e + 2  + e2 < dn) ? u1 : 0;
        int w2 = (e + 4  + e2 < dn) ? u2 : 0;
        int w3 = (e + 6  + e2 < dn) ? u3 : 0;
        int w4 = (e + 8  + e2 < dn) ? u4 : 0;
        int w5 = (e + 10 + e2 < dn) ? u5 : 0;
        int w6 = (e + 12 + e2 < dn) ? u6 : 0;
        int w7 = (e + 14 + e2 < dn) ? u7 : 0;
        H2 p0, p1, p2, p3;
        p0.i = w0; p1.i = w1; p2.i = w2; p3.i = w3;
        a0 += ((float)p0.h[0] + (float)p1.h[0]) + ((float)p2.h[0] + (float)p3.h[0]);
        a1 += ((float)p0.h[1] + (float)p1.h[1]) + ((float)p2.h[1] + (float)p3.h[1]);
        p0.i = w4; p1.i = w5; p2.i = w6; p3.i = w7;
        a0 += ((float)p0.h[0] + (float)p1.h[0]) + ((float)p2.h[0] + (float)p3.h[0]);
        a1 += ((float)p0.h[1] + (float)p1.h[1]) + ((float)p2.h[1] + (float)p3.h[1]);
        u0 = v0; u1 = v1; u2 = v2; u3 = v3;
        u4 = v4; u5 = v5; u6 = v6; u7 = v7;
        colv = coln; coln = colnn;
    }
    a0 += __shfl_xor(a0, 8);           // combine edge halves
    a1 += __shfl_xor(a1, 8);
    {   // self-loop
        H2 p; p.i = s2i[nld * 8 + cd];
        a0 += (float)p.h[0];
        a1 += (float)p.h[1];
    }
    if (n < N && e2 == 0) {
        float di = dinv[nld];
        float2 b = ((const float2*)b2)[cd];
        float2 o;
        o.x = a0 * di + b.x;
        o.y = a1 * di + b.y;
        ((float2*)out)[(size_t)n * 8 + cd] = o;
    }
}

extern "C" void kernel_launch(void* const* d_in, const int* in_sizes, int n_in,
                              void* d_out, int out_size, void* d_ws, size_t ws_size,
                              hipStream_t stream) {
    const int*   x   = (const int*)d_in[0];
    const int*   ei  = (const int*)d_in[1];
    const float* emb = (const float*)d_in[2];
    const float* W1  = (const float*)d_in[3];
    const float* b1  = (const float*)d_in[4];
    const float* W2  = (const float*)d_in[5];
    const float* b2  = (const float*)d_in[6];
    float* out = (float*)d_out;

    const int N = in_sizes[0];
    const int E = in_sizes[1] / 2;
    const int* srcp = ei;
    const int* dstp = ei + E;
    const int NBINS = (N + BIN - 1) >> BINSHIFT;   // 782 for N=100000
    const int NB2 = (NBINS + 1) >> 1;              // 391 bin pairs

    auto al = [](size_t b) { return (b + 255) & ~size_t(255); };
    char* w = (char*)d_ws;
    auto carve = [&](size_t bytes) {
        void* p = (void*)w;
        w += al(bytes);
        return p;
    };
    // no unions: binsort writes sig1 while other blocks still read packed.
    int*   row_start = (int*)carve((size_t)(N + 1) * 4);
    float* dinv      = (float*)carve((size_t)N * 4);
    int*   col       = (int*)carve((size_t)(E + 256) * 4);  // +pad for clamped reads
    unsigned long long* gbin64 = (unsigned long long*)carve((size_t)NB2 * 8);
    int*   packed    = (int*)carve((size_t)NBINS * BINSTRIDE * 4);
    _Float16* sig1   = (_Float16*)carve((size_t)N * 32 * 2);
    _Float16* sig2   = (_Float16*)carve((size_t)N * 16 * 2);
    (void)ws_size; (void)n_in; (void)out_size;

    hipMemsetAsync(gbin64, 0, (size_t)NB2 * 8, stream);
    k_scatter<<<NBLK, BSBIG, 0, stream>>>(srcp, dstp, E, NBINS, gbin64, packed);
    k_binsort<<<NBINS, BS, 0, stream>>>(packed, gbin64, NBINS, N, E,
                                        x, emb, W1, row_start, dinv, col, sig1);

    int gA = (N + 15) / 16;            // 4 waves x 4 nodes per block
    k_agg1mm2<<<gA, BS, 0, stream>>>(sig1, row_start, dinv, col, b1, W2, N, sig2);
    k_agg2<<<gA, BS, 0, stream>>>(sig2, row_start, dinv, col, b2, N, out);
}

// Round 10
// 147.079 us; speedup vs baseline: 1.0237x; 1.0171x over previous
//
#include <hip/hip_runtime.h>

// 2-layer GCN: h1 = emb[x] @ W1; agg+b1+relu; @ W2; agg+b2.
// CSR built per-launch via two-level binned counting sort (no global atomics
// per edge -- R23 measured why: atomic CSR k_deg alone = 429us, WRITE 89MB,
// VALUBusy 0.07%: random global atomics thrash the 8 incoherent L2s).
// R29 = FINAL: R24 verbatim (best measured, 147.6us). Plateau ledger -- every
// lever class probed bidirectionally, all at measured balance:
//   agg TLP:        R20 4x waves +30us | R25 1/3 waves +5.8us
//   agg latency:    R24 pipeline -0.6  | R26 wide preload +0.9 (noise)
//   bin width:      R22 256->128 -2.2  | R27 128->64 +3
//   fusion/launch:  R21 neutral        | R13 cooperative: rejected
//   atomics:        R28 paired-64b neutral | R23 per-edge global +520us
// Residual time: ~100MB cache-resident random row-gathers (issue-bound at
// TLP optimum; agg2 HBM FETCH only 17.6MB) + 12.8M LDS-atomic counting-sort
// ops + forced 4-kernel dependency chain (agg1<-binsort fusion forbidden:
// source-node sig1 incomplete until all binsort blocks retire).
// Rejected by measurement: LDS-atomic edge-parallel agg (R3); 16B-per-lane
// gathers (R10); channel-split passes (R7); cooperative fused build (R13);
// degree-sorted scheduling (R15); atomic-counter scan fusion w/ device fence
// (R16); one-node-per-wave agg (R20); launch-count reduction (R21);
// global-atomic CSR (R23); persistent grid-stride aggs (R25); wide-MLP
// preload (R26); BINSHIFT 6 (R27); paired 64-bit reservation atomics (R28).

#define BS   256
#define BSBIG 1024        // scatter block size (16 waves)
#define NBLK 256          // blocks for scatter
#define BINSHIFT 7        // 128 nodes per bin
#define BIN  128
#define MAXBINS 1024
#define BINCAP 2560       // LDS packed staging (mean bin = 2046, sigma ~45)
#define BINSTRIDE 2560    // slack region per bin in packed (+11 sigma)

union H2 { int i; _Float16 h[2]; };

// ---- fused pass A+B+C: hist (LDS) -> global base alloc -> scatter ----------
__global__ __launch_bounds__(BSBIG) void k_scatter(
    const int* __restrict__ src, const int* __restrict__ dst,
    int E, int NBINS, int* __restrict__ gbin, int* __restrict__ packed) {
    __shared__ int h[MAXBINS];
    __shared__ int cur[MAXBINS];
    int t = threadIdx.x;
    for (int i = t; i < NBINS; i += BSBIG) h[i] = 0;
    __syncthreads();
    int E4 = E >> 2;
    const int4* d4 = (const int4*)dst;
    const int4* s4 = (const int4*)src;
    // phase 1: LDS histogram of this block's slice (+ tail on block 0)
    for (int i = blockIdx.x * BSBIG + t; i < E4; i += NBLK * BSBIG) {
        int4 d = d4[i];
        atomicAdd(&h[d.x >> BINSHIFT], 1);
        atomicAdd(&h[d.y >> BINSHIFT], 1);
        atomicAdd(&h[d.z >> BINSHIFT], 1);
        atomicAdd(&h[d.w >> BINSHIFT], 1);
    }
    if (blockIdx.x == 0 && t < (E & 3))
        atomicAdd(&h[dst[(E4 << 2) + t] >> BINSHIFT], 1);
    __syncthreads();
    // phase 2: one global atomicAdd per bin -> base within slack region
    for (int i = t; i < NBINS; i += BSBIG)
        cur[i] = i * BINSTRIDE + atomicAdd(&gbin[i], h[i]);
    __syncthreads();
    // phase 3: scatter (dst slice is L1/L2-hot from phase 1)
    for (int i = blockIdx.x * BSBIG + t; i < E4; i += NBLK * BSBIG) {
        int4 s = s4[i];
        int4 d = d4[i];
        int p0 = atomicAdd(&cur[d.x >> BINSHIFT], 1);
        packed[p0] = s.x | ((d.x & (BIN - 1)) << 18);
        int p1 = atomicAdd(&cur[d.y >> BINSHIFT], 1);
        packed[p1] = s.y | ((d.y & (BIN - 1)) << 18);
        int p2 = atomicAdd(&cur[d.z >> BINSHIFT], 1);
        packed[p2] = s.z | ((d.z & (BIN - 1)) << 18);
        int p3 = atomicAdd(&cur[d.w >> BINSHIFT], 1);
        packed[p3] = s.w | ((d.w & (BIN - 1)) << 18);
    }
    if (blockIdx.x == 0 && t < (E & 3)) {
        int e = (E4 << 2) + t;
        int d = dst[e];
        int p = atomicAdd(&cur[d >> BINSHIFT], 1);
        packed[p] = src[e] | ((d & (BIN - 1)) << 18);
    }
}

// ---- pass D: per-bin counting sort (staged in LDS) + fused mm1 --------------
// e0 (global CSR base for this bin) = prefix REDUCTION over gbin[0..b-1]
// (shfl tree + 1 barrier; full scan not needed -- only one prefix per block).
__global__ void k_binsort(const int* __restrict__ packed,
                          const int* __restrict__ gbin,
                          int NBINS, int N, int E,
                          const int* __restrict__ x, const float* __restrict__ emb,
                          const float* __restrict__ W1,
                          int* __restrict__ row_start, float* __restrict__ dinv,
                          int* __restrict__ col, _Float16* __restrict__ sig1) {
    __shared__ int buf[BINCAP];                  // 10 KB staging
    __shared__ int ldeg[BIN];
    __shared__ int cur[BIN];
    __shared__ float sW[512];                    // W1 (16x32)
    __shared__ int redw[4];                      // e0 reduction
    __shared__ int wtot[2];                      // ldeg scan wave totals
    int b = blockIdx.x;
    int t = threadIdx.x;
    int lane = t & 63;
    int wv = t >> 6;
    int node0 = b << BINSHIFT;
    // ---- e0 = sum of gbin[0..b-1] (reduction, not scan) ----
    int ps = 0;
    for (int i = t; i < b; i += BS) ps += gbin[i];
    #pragma unroll
    for (int off = 1; off < 64; off <<= 1) ps += __shfl_xor(ps, off);
    if (lane == 0) redw[wv] = ps;
    sW[t] = W1[t];                               // overlap with reduction
    sW[t + 256] = W1[t + 256];
    if (t < BIN) ldeg[t] = 0;
    if (b == 0 && t == 0) row_start[N] = E;      // sentinel
    __syncthreads();
    int e0 = redw[0] + redw[1] + redw[2] + redw[3];
    int cnt = gbin[b];
    int p0 = b * BINSTRIDE;                      // packed region base
    bool fits = (cnt <= BINCAP);                 // uniform per block
    if (fits)
        for (int i = t; i < cnt; i += BS) buf[i] = packed[p0 + i];
    __syncthreads();
    for (int i = t; i < cnt; i += BS) {
        int v = fits ? buf[i] : packed[p0 + i];
        atomicAdd(&ldeg[((unsigned)v >> 18) & (BIN - 1)], 1);
    }
    __syncthreads();
    // ---- exclusive scan of ldeg[128] via 2-wave shfl scan (1 barrier) ----
    int myDeg = 0, inc = 0;
    if (t < BIN) {
        myDeg = ldeg[t];
        inc = myDeg;
        #pragma unroll
        for (int off = 1; off < 64; off <<= 1) {
            int tmp = __shfl_up(inc, off);
            if (lane >= off) inc += tmp;
        }
        if (lane == 63) wtot[wv] = inc;
    }
    __syncthreads();
    if (t < BIN) {
        int pre = (wv == 1) ? wtot[0] : 0;
        int ex = (inc - myDeg) + pre;
        cur[t] = ex;
        int n = node0 + t;
        if (n < N) {
            row_start[n] = e0 + ex;
            dinv[n] = rsqrtf((float)(myDeg + 1));
        }
    }
    __syncthreads();
    for (int i = t; i < cnt; i += BS) {
        int v = fits ? buf[i] : packed[p0 + i];
        int pos = atomicAdd(&cur[((unsigned)v >> 18) & (BIN - 1)], 1);
        col[e0 + pos] = v & 0x3FFFF;
    }
    // ---- fused mm1: 2 threads per node (16 channels each) ----
    int nl = t & (BIN - 1);
    int half = t >> 7;                           // 0 or 1
    int n = node0 + nl;
    if (n < N) {
        float di = rsqrtf((float)(ldeg[nl] + 1));
        const float4* er = (const float4*)(emb + (size_t)x[n] * 16);
        float4 ra = er[0], rb = er[1], rc = er[2], rd = er[3];
        float ev[16] = {ra.x, ra.y, ra.z, ra.w, rb.x, rb.y, rb.z, rb.w,
                        rc.x, rc.y, rc.z, rc.w, rd.x, rd.y, rd.z, rd.w};
        int4* s1o = (int4*)sig1;
        #pragma unroll
        for (int cq2 = 0; cq2 < 2; cq2++) {
            int cq = half * 2 + cq2;
            H2 pk[4];
            #pragma unroll
            for (int dw = 0; dw < 4; dw++) {
                int c = cq * 8 + dw * 2;
                float acc0 = 0.f, acc1 = 0.f;
                #pragma unroll
                for (int k = 0; k < 16; k++) {
                    acc0 += ev[k] * sW[k * 32 + c];
                    acc1 += ev[k] * sW[k * 32 + c + 1];
                }
                pk[dw].h[0] = (_Float16)(acc0 * di);
                pk[dw].h[1] = (_Float16)(acc1 * di);
            }
            int4 pv;
            pv.x = pk[0].i; pv.y = pk[1].i; pv.z = pk[2].i; pv.w = pk[3].i;
            s1o[(size_t)n * 4 + cq] = pv;
        }
    }
}

// ---- fused layer-1 aggregate + b1 + relu + GEMM W2 -> sig2 (fp16) -----------
// 4 NODES per wave: lane = (node g in [0,4)) x (dword-channel cd in [0,16)).
// PIPELINED: iter k issues group k+1's 8 gathers before consuming group k's
// (col prefetched 2 groups ahead) -> consume waits at vmcnt(9), not drain.
__global__ __launch_bounds__(BS) void k_agg1mm2(
    const _Float16* __restrict__ sig1, const int* __restrict__ row_start,
    const float* __restrict__ dinv, const int* __restrict__ col,
    const float* __restrict__ b1, const float* __restrict__ W2,
    int N, _Float16* __restrict__ sig2) {
    __shared__ float hbuf[4][4][36];   // [wave][node][32 ch + pad]
    int t = threadIdx.x;
    int lane = t & 63;
    int wid = t >> 6;
    int g  = lane >> 4;                // node within wave
    int cd = lane & 15;                // dword channel (2 fp16)
    int n = blockIdx.x * 16 + wid * 4 + g;
    int nld = (n < N) ? n : N - 1;
    int rs = row_start[nld];
    int re = row_start[nld + 1];
    int dn = (n < N) ? (re - rs) : 0;
    int dnm1 = (dn > 0) ? dn - 1 : 0;
    int dm = dn;                       // wave max degree
    dm = max(dm, __shfl_xor(dm, 16));
    dm = max(dm, __shfl_xor(dm, 32));
    const int* s1i = (const int*)sig1;
    float a0 = 0.f, a1 = 0.f;
    int iters = (dm + 7) >> 3;
    int slot = cd & 7;
    int bidx = lane & 48;              // group base lane
    int colv = 0, coln = 0;
    if (iters > 0) {
        int idx = slot; if (idx > dnm1) idx = dnm1;
        colv = col[rs + idx];
    }
    if (iters > 1) {
        int idx = 8 + slot; if (idx > dnm1) idx = dnm1;
        coln = col[rs + idx];
    }
    // prologue: issue group 0's gathers
    int u0 = 0, u1 = 0, u2 = 0, u3 = 0, u4 = 0, u5 = 0, u6 = 0, u7 = 0;
    if (iters > 0) {
        int s0 = __shfl(colv, bidx + 0);
        int s1 = __shfl(colv, bidx + 1);
        int s2 = __shfl(colv, bidx + 2);
        int s3 = __shfl(colv, bidx + 3);
        int s4 = __shfl(colv, bidx + 4);
        int s5 = __shfl(colv, bidx + 5);
        int s6 = __shfl(colv, bidx + 6);
        int s7 = __shfl(colv, bidx + 7);
        u0 = s1i[s0 * 16 + cd];        // 8 rows (64B lines) in flight
        u1 = s1i[s1 * 16 + cd];
        u2 = s1i[s2 * 16 + cd];
        u3 = s1i[s3 * 16 + cd];
        u4 = s1i[s4 * 16 + cd];
        u5 = s1i[s5 * 16 + cd];
        u6 = s1i[s6 * 16 + cd];
        u7 = s1i[s7 * 16 + cd];
    }
    for (int it = 0; it < iters; it++) {
        int colnn = 0;
        if (it + 2 < iters) {
            int idx = ((it + 2) << 3) + slot; if (idx > dnm1) idx = dnm1;
            colnn = col[rs + idx];     // col prefetch 2 groups ahead
        }
        // issue NEXT group's gathers before consuming current
        int v0 = 0, v1 = 0, v2 = 0, v3 = 0, v4 = 0, v5 = 0, v6 = 0, v7 = 0;
        if (it + 1 < iters) {
            int s0 = __shfl(coln, bidx + 0);
            int s1 = __shfl(coln, bidx + 1);
            int s2 = __shfl(coln, bidx + 2);
            int s3 = __shfl(coln, bidx + 3);
            int s4 = __shfl(coln, bidx + 4);
            int s5 = __shfl(coln, bidx + 5);
            int s6 = __shfl(coln, bidx + 6);
            int s7 = __shfl(coln, bidx + 7);
            v0 = s1i[s0 * 16 + cd];
            v1 = s1i[s1 * 16 + cd];
            v2 = s1i[s2 * 16 + cd];
            v3 = s1i[s3 * 16 + cd];
            v4 = s1i[s4 * 16 + cd];
            v5 = s1i[s5 * 16 + cd];
            v6 = s1i[s6 * 16 + cd];
            v7 = s1i[s7 * 16 + cd];
        }
        // consume current group (waits only for u0..u7: vmcnt(9))
        int e = it << 3;
        int w0 = (e + 0 < dn) ? u0 : 0;    // 0x0 == +0.0 fp16 pair
        int w1 = (e + 1 < dn) ? u1 : 0;
        int w2 = (e + 2 < dn) ? u2 : 0;
        int w3 = (e + 3 < dn) ? u3 : 0;
        int w4 = (e + 4 < dn) ? u4 : 0;
        int w5 = (e + 5 < dn) ? u5 : 0;
        int w6 = (e + 6 < dn) ? u6 : 0;
        int w7 = (e + 7 < dn) ? u7 : 0;
        H2 p0, p1, p2, p3;
        p0.i = w0; p1.i = w1; p2.i = w2; p3.i = w3;
        a0 += ((float)p0.h[0] + (float)p1.h[0]) + ((float)p2.h[0] + (float)p3.h[0]);
        a1 += ((float)p0.h[1] + (float)p1.h[1]) + ((float)p2.h[1] + (float)p3.h[1]);
        p0.i = w4; p1.i = w5; p2.i = w6; p3.i = w7;
        a0 += ((float)p0.h[0] + (float)p1.h[0]) + ((float)p2.h[0] + (float)p3.h[0]);
        a1 += ((float)p0.h[1] + (float)p1.h[1]) + ((float)p2.h[1] + (float)p3.h[1]);
        u0 = v0; u1 = v1; u2 = v2; u3 = v3;
        u4 = v4; u5 = v5; u6 = v6; u7 = v7;
        colv = coln; coln = colnn;
    }
    {   // self-loop (pre-scaled row)
        H2 p; p.i = s1i[nld * 16 + cd];
        a0 += (float)p.h[0];
        a1 += (float)p.h[1];
    }
    float di = dinv[nld];
    float2 b = ((const float2*)b1)[cd];
    float h0 = fmaxf(a0 * di + b.x, 0.f);
    float h1 = fmaxf(a1 * di + b.y, 0.f);
    float* hb = hbuf[wid][g];
    *(float2*)&hb[2 * cd] = make_float2(h0, h1);
    // w2c loaded HERE (epilogue-only use; keeps main-loop VGPR pressure low,
    // and the global loads cover the ds_write->ds_read latency)
    float w2c[32];
    #pragma unroll
    for (int k = 0; k < 32; k++) w2c[k] = W2[k * 16 + cd];
    // same-wave LDS produce->consume: in-order ds ops + lgkmcnt, no barrier
    float a = 0.f;
    #pragma unroll
    for (int k = 0; k < 32; k += 4) {
        float4 hv = *(const float4*)&hb[k];
        a = fmaf(hv.x, w2c[k],     a);
        a = fmaf(hv.y, w2c[k + 1], a);
        a = fmaf(hv.z, w2c[k + 2], a);
        a = fmaf(hv.w, w2c[k + 3], a);
    }
    if (n < N) sig2[(size_t)n * 16 + cd] = (_Float16)(a * di);   // pre-scale
}

// ---- layer-2 aggregate + b2 -> out ------------------------------------------
// 4 NODES per wave: lane = (node g) x (edge-half e2) x (dword cd in [0,8)).
// PIPELINED like agg1: next group's 8 gathers issued before consuming current.
__global__ __launch_bounds__(BS) void k_agg2(
    const _Float16* __restrict__ sig2, const int* __restrict__ row_start,
    const float* __restrict__ dinv, const int* __restrict__ col,
    const float* __restrict__ b2, int N, float* __restrict__ out) {
    int t = threadIdx.x;
    int lane = t & 63;
    int g  = lane >> 4;                // node within wave
    int e2 = (lane >> 3) & 1;          // edge half
    int cd = lane & 7;                 // dword channel (2 fp16)
    int n = blockIdx.x * 16 + (t >> 6) * 4 + g;
    int nld = (n < N) ? n : N - 1;
    int rs = row_start[nld];
    int re = row_start[nld + 1];
    int dn = (n < N) ? (re - rs) : 0;
    int dnm1 = (dn > 0) ? dn - 1 : 0;
    int dm = dn;
    dm = max(dm, __shfl_xor(dm, 16));
    dm = max(dm, __shfl_xor(dm, 32));
    const int* s2i = (const int*)sig2;
    float a0 = 0.f, a1 = 0.f;
    int iters = (dm + 15) >> 4;
    int slot = lane & 15;              // this lane's col slot (0..15)
    int bidx = lane & 48;
    int colv = 0, coln = 0;
    if (iters > 0) {
        int idx = slot; if (idx > dnm1) idx = dnm1;
        colv = col[rs + idx];
    }
    if (iters > 1) {
        int idx = 16 + slot; if (idx > dnm1) idx = dnm1;
        coln = col[rs + idx];
    }
    // prologue: issue group 0's gathers (8 per lane; each inst = 8 rows)
    int u0 = 0, u1 = 0, u2 = 0, u3 = 0, u4 = 0, u5 = 0, u6 = 0, u7 = 0;
    if (iters > 0) {
        int s0 = __shfl(colv, bidx + 0 + e2);
        int s1 = __shfl(colv, bidx + 2 + e2);
        int s2 = __shfl(colv, bidx + 4 + e2);
        int s3 = __shfl(colv, bidx + 6 + e2);
        int s4 = __shfl(colv, bidx + 8 + e2);
        int s5 = __shfl(colv, bidx + 10 + e2);
        int s6 = __shfl(colv, bidx + 12 + e2);
        int s7 = __shfl(colv, bidx + 14 + e2);
        u0 = s2i[s0 * 8 + cd];
        u1 = s2i[s1 * 8 + cd];
        u2 = s2i[s2 * 8 + cd];
        u3 = s2i[s3 * 8 + cd];
        u4 = s2i[s4 * 8 + cd];
        u5 = s2i[s5 * 8 + cd];
        u6 = s2i[s6 * 8 + cd];
        u7 = s2i[s7 * 8 + cd];
    }
    for (int it = 0; it < iters; it++) {
        int colnn = 0;
        if (it + 2 < iters) {
            int idx = ((it + 2) << 4) + slot; if (idx > dnm1) idx = dnm1;
            colnn = col[rs + idx];     // col prefetch 2 groups ahead
        }
        int v0 = 0, v1 = 0, v2 = 0, v3 = 0, v4 = 0, v5 = 0, v6 = 0, v7 = 0;
        if (it + 1 < iters) {
            int s0 = __shfl(coln, bidx + 0 + e2);
            int s1 = __shfl(coln, bidx + 2 + e2);
            int s2 = __shfl(coln, bidx + 4 + e2);
            int s3 = __shfl(coln, bidx + 6 + e2);
            int s4 = __shfl(coln, bidx + 8 + e2);
            int s5 = __shfl(coln, bidx + 10 + e2);
            int s6 = __shfl(coln, bidx + 12 + e2);
            int s7 = __shfl(coln, bidx + 14 + e2);
            v0 = s2i[s0 * 8 + cd];
            v1 = s2i[s1 * 8 + cd];
            v2 = s2i[s2 * 8 + cd];
            v3 = s2i[s3 * 8 + cd];
            v4 = s2i[s4 * 8 + cd];
            v5 = s2i[s5 * 8 + cd];
            v6 = s2i[s6 * 8 + cd];
            v7 = s2i[s7 * 8 + cd];
        }
        int e = it << 4;
        int w0 = (e + 0  + e2 < dn) ? u0 : 0;
        int w1 = (e + 2  + e2 < dn) ? u1 : 0;
        int w2 = (e + 4  + e2 < dn) ? u2 : 0;
        int w3 = (e + 6  + e2 < dn) ? u3 : 0;
        int w4 = (e + 8  + e2 < dn) ? u4 : 0;
        int w5 = (e + 10 + e2 < dn) ? u5 : 0;
        int w6 = (e + 12 + e2 < dn) ? u6 : 0;
        int w7 = (e + 14 + e2 < dn) ? u7 : 0;
        H2 p0, p1, p2, p3;
        p0.i = w0; p1.i = w1; p2.i = w2; p3.i = w3;
        a0 += ((float)p0.h[0] + (float)p1.h[0]) + ((float)p2.h[0] + (float)p3.h[0]);
        a1 += ((float)p0.h[1] + (float)p1.h[1]) + ((float)p2.h[1] + (float)p3.h[1]);
        p0.i = w4; p1.i = w5; p2.i = w6; p3.i = w7;
        a0 += ((float)p0.h[0] + (float)p1.h[0]) + ((float)p2.h[0] + (float)p3.h[0]);
        a1 += ((float)p0.h[1] + (float)p1.h[1]) + ((float)p2.h[1] + (float)p3.h[1]);
        u0 = v0; u1 = v1; u2 = v2; u3 = v3;
        u4 = v4; u5 = v5; u6 = v6; u7 = v7;
        colv = coln; coln = colnn;
    }
    a0 += __shfl_xor(a0, 8);           // combine edge halves
    a1 += __shfl_xor(a1, 8);
    {   // self-loop
        H2 p; p.i = s2i[nld * 8 + cd];
        a0 += (float)p.h[0];
        a1 += (float)p.h[1];
    }
    if (n < N && e2 == 0) {
        float di = dinv[nld];
        float2 b = ((const float2*)b2)[cd];
        float2 o;
        o.x = a0 * di + b.x;
        o.y = a1 * di + b.y;
        ((float2*)out)[(size_t)n * 8 + cd] = o;
    }
}

extern "C" void kernel_launch(void* const* d_in, const int* in_sizes, int n_in,
                              void* d_out, int out_size, void* d_ws, size_t ws_size,
                              hipStream_t stream) {
    const int*   x   = (const int*)d_in[0];
    const int*   ei  = (const int*)d_in[1];
    const float* emb = (const float*)d_in[2];
    const float* W1  = (const float*)d_in[3];
    const float* b1  = (const float*)d_in[4];
    const float* W2  = (const float*)d_in[5];
    const float* b2  = (const float*)d_in[6];
    float* out = (float*)d_out;

    const int N = in_sizes[0];
    const int E = in_sizes[1] / 2;
    const int* srcp = ei;
    const int* dstp = ei + E;
    const int NBINS = (N + BIN - 1) >> BINSHIFT;   // 782 for N=100000

    auto al = [](size_t b) { return (b + 255) & ~size_t(255); };
    char* w = (char*)d_ws;
    auto carve = [&](size_t bytes) {
        void* p = (void*)w;
        w += al(bytes);
        return p;
    };
    // no unions: binsort writes sig1 while other blocks still read packed.
    int*   row_start = (int*)carve((size_t)(N + 1) * 4);
    float* dinv      = (float*)carve((size_t)N * 4);
    int*   col       = (int*)carve((size_t)(E + 256) * 4);  // +pad for clamped reads
    int*   gbin      = (int*)carve((size_t)NBINS * 4);
    int*   packed    = (int*)carve((size_t)NBINS * BINSTRIDE * 4);
    _Float16* sig1   = (_Float16*)carve((size_t)N * 32 * 2);
    _Float16* sig2   = (_Float16*)carve((size_t)N * 16 * 2);
    (void)ws_size; (void)n_in; (void)out_size;

    hipMemsetAsync(gbin, 0, (size_t)NBINS * 4, stream);
    k_scatter<<<NBLK, BSBIG, 0, stream>>>(srcp, dstp, E, NBINS, gbin, packed);
    k_binsort<<<NBINS, BS, 0, stream>>>(packed, gbin, NBINS, N, E,
                                        x, emb, W1, row_start, dinv, col, sig1);

    int gA = (N + 15) / 16;            // 4 waves x 4 nodes per block
    k_agg1mm2<<<gA, BS, 0, stream>>>(sig1, row_start, dinv, col, b1, W2, N, sig2);
    k_agg2<<<gA, BS, 0, stream>>>(sig2, row_start, dinv, col, b2, N, out);
}